// Round 1
// baseline (319.708 us; speedup 1.0000x reference)
//
#include <hip/hip_runtime.h>
#include <hip/hip_bf16.h>

// Problem constants
#define NN 100000
#define DD 128
#define BB 4096
#define KK 64
#define HH 256
#define EE 128

typedef __bf16 bf16x8 __attribute__((ext_vector_type(8)));
typedef float f32x4 __attribute__((ext_vector_type(4)));

// ---- workspace layout (element offsets into __bf16* base; bytes = 2x) ----
// frag blocks: each frag = 64 lanes x 16B = 1KB = 512 bf16 elems
#define EL_W1A 0        // 16nt x 4kk = 64 frags
#define EL_W1B 32768    // 8nt x 8kk  = 64 frags
#define EL_WIH 65536    // 64nt x 4kk = 256 frags
#define EL_WHH 196608   // 64nt x 8kk = 512 frags
#define EL_W3  458752   // 8nt x 8kk  = 64 frags
#define EL_W2B 491520   // 16nt x 4kk = 64 frags
#define EL_W2A 524288   // 16nt x 4kk = 64 frags
// fp32 regions (byte offsets)
#define BOFF_T     2097152   // t[B][256] fp32 = 4MB
#define BOFF_CONST 6291456   // const[B] fp32

__device__ __forceinline__ float sigmoid_f(float x){ return 1.0f/(1.0f+__expf(-x)); }
__device__ __forceinline__ float tanh_f(float x){ return 1.0f - 2.0f/(__expf(2.0f*x)+1.0f); }

__device__ __forceinline__ bf16x8 pack8(float4 a, float4 b){
    bf16x8 v;
    v[0]=(__bf16)a.x; v[1]=(__bf16)a.y; v[2]=(__bf16)a.z; v[3]=(__bf16)a.w;
    v[4]=(__bf16)b.x; v[5]=(__bf16)b.y; v[6]=(__bf16)b.z; v[7]=(__bf16)b.w;
    return v;
}

// ---------------- weight swizzle: fp32 -> bf16 MFMA B-fragment layout -------
// B-frag layout for mfma_f32_16x16x32_bf16: lane l holds B[k][n] with
// n = nt*16 + (l&15), k = kk*32 + (l>>4)*8 + j, j=0..7.
__global__ __launch_bounds__(64) void swz_kernel(
    const float* __restrict__ W1a, const float* __restrict__ W1b,
    const float* __restrict__ Wih, const float* __restrict__ Whh,
    const float* __restrict__ W3,  const float* __restrict__ W2b,
    const float* __restrict__ W2a, __bf16* __restrict__ wsbf)
{
    int g = blockIdx.x, lane = threadIdx.x;
    int quad = lane >> 4, l15 = lane & 15;
    const float* src; int stride, nkk, local; long dst; bool kn = false;
    if      (g <  64){ src=W1a; stride=129; nkk=4; dst=EL_W1A; local=g;      }
    else if (g < 128){ src=W1b; stride=256; nkk=8; dst=EL_W1B; local=g-64;   }
    else if (g < 384){ src=Wih; stride=128; nkk=4; dst=EL_WIH; local=g-128;  }
    else if (g < 896){ src=Whh; stride=256; nkk=8; dst=EL_WHH; local=g-384;  }
    else if (g < 960){ src=W3;  stride=256; nkk=8; dst=EL_W3;  local=g-896;  }
    else if (g <1024){ src=W2b; stride=256; nkk=4; dst=EL_W2B; local=g-960; kn=true; }
    else             { src=W2a; stride=129; nkk=4; dst=EL_W2A; local=g-1024; }
    int nt = local / nkk, kk = local % nkk;
    int n = nt*16 + l15, k0 = kk*32 + quad*8;
    bf16x8 v;
#pragma unroll
    for (int j = 0; j < 8; ++j){
        float x = kn ? src[(long)(k0+j)*stride + n] : src[(long)n*stride + k0 + j];
        v[j] = (__bf16)x;
    }
    ((bf16x8*)(wsbf + dst))[local*64 + lane] = v;
}

// ---------------- action path: MLP1 -> LSTM -> MLP3 -> t = W2b^T emb -------
// 128 blocks x 256 threads; block handles 32 batch rows.
__global__ __launch_bounds__(256) void act_kernel(
    const float* __restrict__ node_pre, const float* __restrict__ steps,
    const float* __restrict__ h0, const float* __restrict__ c0,
    const float* __restrict__ W1a, const float* __restrict__ b1a,
    const float* __restrict__ b1b, const float* __restrict__ bih,
    const float* __restrict__ bhh, const float* __restrict__ b3,
    const float* __restrict__ b2b, const int* __restrict__ actions0,
    const __bf16* __restrict__ wsbf,
    float* __restrict__ out_h, float* __restrict__ out_c,
    float* __restrict__ t_ws, float* __restrict__ const_ws)
{
    __shared__ __bf16 apre[32*136];   // a_pre; reused as x after S1
    __shared__ __bf16 x1s [32*264];   // x1; reused as emb (stride 136) after S2
    __shared__ __bf16 h0s [32*264];
    __shared__ __bf16 hss [32*264];
    __shared__ float b1a_s[256], w1acol_s[256], b1b_s[128], gb_s[1024];
    __shared__ float b3_s[128], b2b_s[128], sb_s[32];

    int tid = threadIdx.x, blk = blockIdx.x;
    int b0 = blk * 32;

    // stage biases
    { int h = tid; b1a_s[h & 255] = b1a_s[h & 255]; } // no-op placeholder removed below
    if (tid < 256){ b1a_s[tid] = b1a[tid]; w1acol_s[tid] = W1a[tid*129 + 128]; }
    if (tid < 128){ b1b_s[tid] = b1b[tid]; b3_s[tid] = b3[tid]; b2b_s[tid] = b2b[tid]; }
    for (int j = tid; j < 1024; j += 256) gb_s[j] = bih[j] + bhh[j];
    if (tid < 32) sb_s[tid] = steps[b0 + tid] * 0.01f;

    // stage a_pre (gather): row = tid>>3, 8 threads/row, 16 cols each
    {
        int r = tid >> 3, seg = tid & 7;
        long a0 = actions0[b0 + r];
        const float4* sp = (const float4*)(node_pre + a0*128 + seg*16);
        float4 f0 = sp[0], f1 = sp[1], f2 = sp[2], f3 = sp[3];
        *(bf16x8*)&apre[r*136 + seg*16    ] = pack8(f0, f1);
        *(bf16x8*)&apre[r*136 + seg*16 + 8] = pack8(f2, f3);
    }
    // stage h0 rows (contiguous): row = tid>>3, 32 cols each
    {
        int r = tid >> 3, seg = tid & 7;
        const float4* sp = (const float4*)(h0 + (long)(b0 + r)*256 + seg*32);
#pragma unroll
        for (int q = 0; q < 4; ++q){
            float4 fa = sp[q*2], fb = sp[q*2+1];
            *(bf16x8*)&h0s[r*264 + seg*32 + q*8] = pack8(fa, fb);
        }
    }
    __syncthreads();

    int wave = tid >> 6, lane = tid & 63, quad = lane >> 4, l15 = lane & 15;
    const bf16x8* F_W1A = (const bf16x8*)(wsbf + EL_W1A);
    const bf16x8* F_W1B = (const bf16x8*)(wsbf + EL_W1B);
    const bf16x8* F_WIH = (const bf16x8*)(wsbf + EL_WIH);
    const bf16x8* F_WHH = (const bf16x8*)(wsbf + EL_WHH);
    const bf16x8* F_W3  = (const bf16x8*)(wsbf + EL_W3);
    const bf16x8* F_W2B = (const bf16x8*)(wsbf + EL_W2B);

    // ---- S1: x1 = relu(W1a . a_pre + b1a + w1acol*sb), N=256 K=128 ----
    for (int mt = 0; mt < 2; ++mt){
        bf16x8 af[4];
#pragma unroll
        for (int kk = 0; kk < 4; ++kk)
            af[kk] = *(const bf16x8*)&apre[(mt*16 + l15)*136 + kk*32 + quad*8];
#pragma unroll
        for (int j = 0; j < 4; ++j){
            int nt = wave + 4*j;
            f32x4 acc = {0.f,0.f,0.f,0.f};
#pragma unroll
            for (int kk = 0; kk < 4; ++kk)
                acc = __builtin_amdgcn_mfma_f32_16x16x32_bf16(af[kk], F_W1A[(nt*4+kk)*64 + lane], acc, 0,0,0);
            int col = nt*16 + l15;
            float bb = b1a_s[col], wc = w1acol_s[col];
#pragma unroll
            for (int i = 0; i < 4; ++i){
                int r = mt*16 + quad*4 + i;
                float v = acc[i] + bb + wc*sb_s[r];
                x1s[r*264 + col] = (__bf16)fmaxf(v, 0.f);
            }
        }
    }
    __syncthreads();

    // ---- S2: x = x1 @ W1b.T + b1b (no relu), N=128 K=256 -> apre buffer ----
    __bf16* xs = apre;
    for (int mt = 0; mt < 2; ++mt){
        bf16x8 af[8];
#pragma unroll
        for (int kk = 0; kk < 8; ++kk)
            af[kk] = *(const bf16x8*)&x1s[(mt*16 + l15)*264 + kk*32 + quad*8];
#pragma unroll
        for (int j = 0; j < 2; ++j){
            int nt = wave + 4*j;
            f32x4 acc = {0.f,0.f,0.f,0.f};
#pragma unroll
            for (int kk = 0; kk < 8; ++kk)
                acc = __builtin_amdgcn_mfma_f32_16x16x32_bf16(af[kk], F_W1B[(nt*8+kk)*64 + lane], acc, 0,0,0);
            int col = nt*16 + l15;
#pragma unroll
            for (int i = 0; i < 4; ++i){
                int r = mt*16 + quad*4 + i;
                xs[r*136 + col] = (__bf16)(acc[i] + b1b_s[col]);
            }
        }
    }
    __syncthreads();

    // ---- S3: gates = [x|h0] @ [Wih|Whh].T + bih + bhh; LSTM elementwise ----
    for (int mt = 0; mt < 2; ++mt){
        bf16x8 xf[4], hf[8];
#pragma unroll
        for (int kk = 0; kk < 4; ++kk)
            xf[kk] = *(const bf16x8*)&xs[(mt*16 + l15)*136 + kk*32 + quad*8];
#pragma unroll
        for (int kk = 0; kk < 8; ++kk)
            hf[kk] = *(const bf16x8*)&h0s[(mt*16 + l15)*264 + kk*32 + quad*8];
#pragma unroll
        for (int j = 0; j < 4; ++j){
            int bnt = wave + 4*j;  // i-gate tile; f=+16, g=+32, o=+48
            f32x4 ai = {0.f,0.f,0.f,0.f}, afv = ai, ag = ai, ao = ai;
#pragma unroll
            for (int kk = 0; kk < 12; ++kk){
                bf16x8 a = (kk < 4) ? xf[kk] : hf[kk-4];
                if (kk < 4){
                    ai  = __builtin_amdgcn_mfma_f32_16x16x32_bf16(a, F_WIH[((bnt   )*4+kk)*64 + lane], ai , 0,0,0);
                    afv = __builtin_amdgcn_mfma_f32_16x16x32_bf16(a, F_WIH[((bnt+16)*4+kk)*64 + lane], afv, 0,0,0);
                    ag  = __builtin_amdgcn_mfma_f32_16x16x32_bf16(a, F_WIH[((bnt+32)*4+kk)*64 + lane], ag , 0,0,0);
                    ao  = __builtin_amdgcn_mfma_f32_16x16x32_bf16(a, F_WIH[((bnt+48)*4+kk)*64 + lane], ao , 0,0,0);
                } else {
                    int k2 = kk - 4;
                    ai  = __builtin_amdgcn_mfma_f32_16x16x32_bf16(a, F_WHH[((bnt   )*8+k2)*64 + lane], ai , 0,0,0);
                    afv = __builtin_amdgcn_mfma_f32_16x16x32_bf16(a, F_WHH[((bnt+16)*8+k2)*64 + lane], afv, 0,0,0);
                    ag  = __builtin_amdgcn_mfma_f32_16x16x32_bf16(a, F_WHH[((bnt+32)*8+k2)*64 + lane], ag , 0,0,0);
                    ao  = __builtin_amdgcn_mfma_f32_16x16x32_bf16(a, F_WHH[((bnt+48)*8+k2)*64 + lane], ao , 0,0,0);
                }
            }
            int col = bnt*16 + l15;
            float bi = gb_s[col], bf_ = gb_s[col+256], bg = gb_s[col+512], bo = gb_s[col+768];
#pragma unroll
            for (int i = 0; i < 4; ++i){
                int r = mt*16 + quad*4 + i;
                long brow = b0 + r;
                float iv = ai[i]+bi, fv = afv[i]+bf_, gv = ag[i]+bg, ov = ao[i]+bo;
                float c0v = c0[brow*256 + col];
                float cn = sigmoid_f(fv)*c0v + sigmoid_f(iv)*tanh_f(gv);
                float hn = sigmoid_f(ov)*tanh_f(cn);
                out_h[brow*256 + col] = hn;
                out_c[brow*256 + col] = cn;
                hss[r*264 + col] = (__bf16)hn;
            }
        }
    }
    __syncthreads();

    // ---- S4: emb = h @ W3.T + b3, N=128 K=256 -> x1s buffer (stride 136) ----
    __bf16* embs = x1s;
    for (int mt = 0; mt < 2; ++mt){
        bf16x8 af[8];
#pragma unroll
        for (int kk = 0; kk < 8; ++kk)
            af[kk] = *(const bf16x8*)&hss[(mt*16 + l15)*264 + kk*32 + quad*8];
#pragma unroll
        for (int j = 0; j < 2; ++j){
            int nt = wave + 4*j;
            f32x4 acc = {0.f,0.f,0.f,0.f};
#pragma unroll
            for (int kk = 0; kk < 8; ++kk)
                acc = __builtin_amdgcn_mfma_f32_16x16x32_bf16(af[kk], F_W3[(nt*8+kk)*64 + lane], acc, 0,0,0);
            int col = nt*16 + l15;
#pragma unroll
            for (int i = 0; i < 4; ++i){
                int r = mt*16 + quad*4 + i;
                embs[r*136 + col] = (__bf16)(acc[i] + b3_s[col]);
            }
        }
    }
    __syncthreads();

    // const[b] = dot(b2b, emb[b])  (b2b is zeros in this problem, kept for generality)
    if (tid < 32){
        float s = 0.f;
        for (int e = 0; e < 128; ++e) s += b2b_s[e] * (float)embs[tid*136 + e];
        const_ws[b0 + tid] = s;
    }
    // ---- S5: t = W2b^T emb, N=256 K=128 -> global ----
    for (int mt = 0; mt < 2; ++mt){
        bf16x8 af[4];
#pragma unroll
        for (int kk = 0; kk < 4; ++kk)
            af[kk] = *(const bf16x8*)&embs[(mt*16 + l15)*136 + kk*32 + quad*8];
#pragma unroll
        for (int j = 0; j < 4; ++j){
            int nt = wave + 4*j;
            f32x4 acc = {0.f,0.f,0.f,0.f};
#pragma unroll
            for (int kk = 0; kk < 4; ++kk)
                acc = __builtin_amdgcn_mfma_f32_16x16x32_bf16(af[kk], F_W2B[(nt*4+kk)*64 + lane], acc, 0,0,0);
            int col = nt*16 + l15;
#pragma unroll
            for (int i = 0; i < 4; ++i){
                int r = mt*16 + quad*4 + i;
                t_ws[(long)(b0 + r)*256 + col] = acc[i];
            }
        }
    }
}

// ---------------- neighbor path: vals = relu(W2a.pre + bias) . t / sqrt(E) --
// 1024 blocks x 256 threads; block handles 4 batch rows (4 x 64 neighbors).
__global__ __launch_bounds__(256) void nei_kernel(
    const float* __restrict__ node_pre, const float* __restrict__ steps,
    const float* __restrict__ W2a, const float* __restrict__ b2a,
    const int* __restrict__ neighbors, const int* __restrict__ deg,
    const __bf16* __restrict__ wsbf, const float* __restrict__ t_ws,
    const float* __restrict__ const_ws, float* __restrict__ out_vals)
{
    __shared__ __bf16 at[64*136];
    __shared__ float b2a_s[256], w2acol_s[256], t_s[256], vp[4*64];

    int tid = threadIdx.x, blk = blockIdx.x;
    b2a_s[tid] = b2a[tid];
    w2acol_s[tid] = W2a[tid*129 + 128];

    int wave = tid >> 6, lane = tid & 63, quad = lane >> 4, l15 = lane & 15;
    const bf16x8* FB = (const bf16x8*)(wsbf + EL_W2A);
    bf16x8 bw[16];   // wave's 4 n-tiles x 4 k-steps, held in registers
#pragma unroll
    for (int j = 0; j < 4; ++j){
        int nt = wave + 4*j;
#pragma unroll
        for (int kk = 0; kk < 4; ++kk) bw[j*4+kk] = FB[(nt*4+kk)*64 + lane];
    }

    for (int ib = 0; ib < 4; ++ib){
        int b = blk*4 + ib;
        __syncthreads();   // protect at/t_s/vp from previous iteration readers
        // stage gathered neighbor features -> bf16 LDS, row stride 136 (pad)
        {
            int r = tid >> 2, seg = tid & 3;
            long nb = neighbors[b*64 + r];
            const float4* sp = (const float4*)(node_pre + nb*128 + seg*32);
#pragma unroll
            for (int q = 0; q < 4; ++q){
                float4 fa = sp[q*2], fb = sp[q*2+1];
                *(bf16x8*)&at[r*136 + seg*32 + q*8] = pack8(fa, fb);
            }
        }
        t_s[tid] = t_ws[(long)b*256 + tid];
        __syncthreads();

        float sb  = steps[b] * 0.01f;
        float cst = const_ws[b];
        int degb  = deg[b]; if (degb < 1) degb = 1;

        for (int mt = 0; mt < 4; ++mt){
            bf16x8 af[4];
#pragma unroll
            for (int kk = 0; kk < 4; ++kk)
                af[kk] = *(const bf16x8*)&at[(mt*16 + l15)*136 + kk*32 + quad*8];
            f32x4 ps = {0.f,0.f,0.f,0.f};
#pragma unroll
            for (int j = 0; j < 4; ++j){
                int nt = wave + 4*j;
                f32x4 acc = {0.f,0.f,0.f,0.f};
#pragma unroll
                for (int kk = 0; kk < 4; ++kk)
                    acc = __builtin_amdgcn_mfma_f32_16x16x32_bf16(af[kk], bw[j*4+kk], acc, 0,0,0);
                int col = nt*16 + l15;
                float bias = b2a_s[col] + w2acol_s[col]*sb;
                float tv = t_s[col];
#pragma unroll
                for (int i = 0; i < 4; ++i){
                    float hv = fmaxf(acc[i] + bias, 0.f);
                    ps[i] += hv * tv;
                }
            }
            // reduce partial sums across the 16 lanes sharing a quad
#pragma unroll
            for (int m = 1; m < 16; m <<= 1){
#pragma unroll
                for (int i = 0; i < 4; ++i) ps[i] += __shfl_xor(ps[i], m, 64);
            }
            if (l15 == 0){
#pragma unroll
                for (int i = 0; i < 4; ++i) vp[wave*64 + mt*16 + quad*4 + i] = ps[i];
            }
        }
        __syncthreads();
        if (tid < 64){
            float v = vp[tid] + vp[64+tid] + vp[128+tid] + vp[192+tid];
            v = (v + cst) * 0.08838834764831845f;   // 1/sqrt(128)
            if (tid >= degb) v = 0.f;
            out_vals[(long)b*64 + tid] = v;
        }
    }
}

extern "C" void kernel_launch(void* const* d_in, const int* in_sizes, int n_in,
                              void* d_out, int out_size, void* d_ws, size_t ws_size,
                              hipStream_t stream)
{
    (void)in_sizes; (void)n_in; (void)out_size; (void)ws_size;
    const float* node_pre = (const float*)d_in[0];
    const float* steps    = (const float*)d_in[1];
    const float* h0       = (const float*)d_in[2];
    const float* c0       = (const float*)d_in[3];
    const float* W1a      = (const float*)d_in[4];
    const float* b1a      = (const float*)d_in[5];
    const float* W1b      = (const float*)d_in[6];
    const float* b1b      = (const float*)d_in[7];
    const float* W2a      = (const float*)d_in[8];
    const float* b2a      = (const float*)d_in[9];
    const float* W2b      = (const float*)d_in[10];
    const float* b2b      = (const float*)d_in[11];
    const float* W3       = (const float*)d_in[12];
    const float* b3       = (const float*)d_in[13];
    const float* Wih      = (const float*)d_in[14];
    const float* Whh      = (const float*)d_in[15];
    const float* bih      = (const float*)d_in[16];
    const float* bhh      = (const float*)d_in[17];
    const int* actions0   = (const int*)d_in[18];
    const int* neighbors  = (const int*)d_in[19];
    const int* deg        = (const int*)d_in[20];

    float* out      = (float*)d_out;
    float* out_vals = out;                       // [4096][64]
    float* out_h    = out + (long)BB*KK;         // [4096][256]
    float* out_c    = out_h + (long)BB*HH;       // [4096][256]

    __bf16* wsbf    = (__bf16*)d_ws;
    float* t_ws     = (float*)((char*)d_ws + BOFF_T);
    float* const_ws = (float*)((char*)d_ws + BOFF_CONST);

    swz_kernel<<<dim3(1088), dim3(64), 0, stream>>>(W1a, W1b, Wih, Whh, W3, W2b, W2a, wsbf);
    act_kernel<<<dim3(128), dim3(256), 0, stream>>>(node_pre, steps, h0, c0, W1a, b1a, b1b,
                                                    bih, bhh, b3, b2b, actions0, wsbf,
                                                    out_h, out_c, t_ws, const_ws);
    nei_kernel<<<dim3(1024), dim3(256), 0, stream>>>(node_pre, steps, W2a, b2a, neighbors, deg,
                                                     wsbf, t_ws, const_ws, out_vals);
}

// Round 2
// 203.906 us; speedup vs baseline: 1.5679x; 1.5679x over previous
//
#include <hip/hip_runtime.h>
#include <hip/hip_bf16.h>

// Problem constants
#define NN 100000
#define DD 128
#define BB 4096
#define KK 64
#define HH 256
#define EE 128

typedef __bf16 bf16x8 __attribute__((ext_vector_type(8)));
typedef float f32x4 __attribute__((ext_vector_type(4)));

// ---- bf16 frag region (element offsets into __bf16* base) ----
// each frag = 64 lanes x 16B = 1KB = 512 bf16 elems
#define EL_W1A 0        // 16nt x 4kk = 64 frags
#define EL_W1B 32768    // 8nt x 8kk  = 64 frags
#define EL_WIH 65536    // 64nt x 4kk = 256 frags
#define EL_WHH 196608   // 64nt x 8kk = 512 frags
#define EL_W3  458752   // 8nt x 8kk  = 64 frags
#define EL_W2B 491520   // 16nt x 4kk = 64 frags
#define EL_W2A 524288   // 16nt x 4kk = 64 frags
// frag region ends at elem 557056 = byte 0x110000

// ---- fp32 / bf16 workspace regions (byte offsets) ----
#define BOFF_GB     0x110000   // fp32[1024]  bih+bhh
#define BOFF_W1COL  0x111000   // fp32[256]   W1a[:,128]
#define BOFF_W2COL  0x111400   // fp32[256]   W2a[:,128]
#define BOFF_CONST  0x111800   // fp32[4096]
#define BOFF_XT     0x115800   // x bf16[4096][128] (1MB), later t bf16[4096][256] (2MB)
#define BOFF_HBF    0x315800   // h bf16[4096][256] (2MB)
#define BOFF_NODEBF 0x515800   // optional node_pre bf16 [100000][128] (25.6MB)
#define WS_NEED_FULL ((size_t)0x515800 + (size_t)NN*DD*2)

__device__ __forceinline__ float sigmoid_f(float x){ return 1.0f/(1.0f+__expf(-x)); }
__device__ __forceinline__ float tanh_f(float x){ return 1.0f - 2.0f/(__expf(2.0f*x)+1.0f); }

__device__ __forceinline__ bf16x8 pack8(float4 a, float4 b){
    bf16x8 v;
    v[0]=(__bf16)a.x; v[1]=(__bf16)a.y; v[2]=(__bf16)a.z; v[3]=(__bf16)a.w;
    v[4]=(__bf16)b.x; v[5]=(__bf16)b.y; v[6]=(__bf16)b.z; v[7]=(__bf16)b.w;
    return v;
}

// ---------------- node_pre fp32 -> bf16 (optional, FULL path) --------------
__global__ __launch_bounds__(256) void conv_kernel(const float* __restrict__ src,
                                                   __bf16* __restrict__ dst){
    const long total = (long)NN*DD/8;   // 1.6M bf16x8 chunks
    for (long i = (long)blockIdx.x*256 + threadIdx.x; i < total; i += (long)gridDim.x*256){
        const float4* s4 = (const float4*)src + i*2;
        float4 a = s4[0], b = s4[1];
        ((bf16x8*)dst)[i] = pack8(a, b);
    }
}

// ---------------- weight swizzle + misc precompute -------------------------
// B-frag layout for mfma_f32_16x16x32_bf16: lane l holds B[k][n] with
// n = nt*16 + (l&15), k = kk*32 + (l>>4)*8 + j, j=0..7.
__global__ __launch_bounds__(64) void swz_kernel(
    const float* __restrict__ W1a, const float* __restrict__ W1b,
    const float* __restrict__ Wih, const float* __restrict__ Whh,
    const float* __restrict__ W3,  const float* __restrict__ W2b,
    const float* __restrict__ W2a, const float* __restrict__ bih,
    const float* __restrict__ bhh, __bf16* __restrict__ wsbf,
    float* __restrict__ gb_ws, float* __restrict__ w1col_ws,
    float* __restrict__ w2col_ws)
{
    int g = blockIdx.x, lane = threadIdx.x;
    if (g >= 1088){
        if (g < 1104){ int idx = (g-1088)*64 + lane; gb_ws[idx] = bih[idx] + bhh[idx]; }
        else if (g < 1108){ int idx = (g-1104)*64 + lane; w1col_ws[idx] = W1a[idx*129 + 128]; }
        else { int idx = (g-1108)*64 + lane; w2col_ws[idx] = W2a[idx*129 + 128]; }
        return;
    }
    int quad = lane >> 4, l15 = lane & 15;
    const float* src; int stride, nkk, local; long dst; bool kn = false;
    if      (g <  64){ src=W1a; stride=129; nkk=4; dst=EL_W1A; local=g;      }
    else if (g < 128){ src=W1b; stride=256; nkk=8; dst=EL_W1B; local=g-64;   }
    else if (g < 384){ src=Wih; stride=128; nkk=4; dst=EL_WIH; local=g-128;  }
    else if (g < 896){ src=Whh; stride=256; nkk=8; dst=EL_WHH; local=g-384;  }
    else if (g < 960){ src=W3;  stride=256; nkk=8; dst=EL_W3;  local=g-896;  }
    else if (g <1024){ src=W2b; stride=256; nkk=4; dst=EL_W2B; local=g-960; kn=true; }
    else             { src=W2a; stride=129; nkk=4; dst=EL_W2A; local=g-1024; }
    int nt = local / nkk, kk = local % nkk;
    int n = nt*16 + l15, k0 = kk*32 + quad*8;
    bf16x8 v;
#pragma unroll
    for (int j = 0; j < 8; ++j){
        float x = kn ? src[(long)(k0+j)*stride + n] : src[(long)n*stride + k0 + j];
        v[j] = (__bf16)x;
    }
    ((bf16x8*)(wsbf + dst))[local*64 + lane] = v;
}

// ---------------- actA: x = MLP1(a_pre) -> bf16 ws  (16 rows/block) --------
__global__ __launch_bounds__(256) void actA_kernel(
    const float* __restrict__ node_pre, const float* __restrict__ steps,
    const int* __restrict__ actions0, const float* __restrict__ b1a,
    const float* __restrict__ b1b, const float* __restrict__ w1col,
    const __bf16* __restrict__ wsbf, __bf16* __restrict__ x_bf)
{
    __shared__ __bf16 apre[16*136];   // reused as x-out after S1/S2
    __shared__ __bf16 x1s [16*264];
    __shared__ float b1a_s[256], w1c_s[256], b1b_s[128], sb_s[16];

    int tid = threadIdx.x, b0 = blockIdx.x * 16;
    b1a_s[tid] = b1a[tid];
    w1c_s[tid] = w1col[tid];
    if (tid < 128) b1b_s[tid] = b1b[tid];
    if (tid < 16)  sb_s[tid] = steps[b0 + tid] * 0.01f;
    {   // gather a_pre: 16 threads/row x 8 floats
        int r = tid >> 4, seg = tid & 15;
        long a0 = actions0[b0 + r];
        const float4* sp = (const float4*)(node_pre + a0*128 + seg*8);
        float4 f0 = sp[0], f1 = sp[1];
        *(bf16x8*)&apre[r*136 + seg*8] = pack8(f0, f1);
    }
    __syncthreads();

    int wave = tid >> 6, lane = tid & 63, quad = lane >> 4, l15 = lane & 15;
    const bf16x8* F1A = (const bf16x8*)(wsbf + EL_W1A);
    const bf16x8* F1B = (const bf16x8*)(wsbf + EL_W1B);

    // S1: x1 = relu(a_pre @ W1a^T + b1a + w1col*sb), N=256 K=128
    {
        bf16x8 af[4];
#pragma unroll
        for (int kk = 0; kk < 4; ++kk)
            af[kk] = *(const bf16x8*)&apre[l15*136 + kk*32 + quad*8];
#pragma unroll
        for (int j = 0; j < 4; ++j){
            int nt = wave*4 + j;
            f32x4 acc = {0.f,0.f,0.f,0.f};
#pragma unroll
            for (int kk = 0; kk < 4; ++kk)
                acc = __builtin_amdgcn_mfma_f32_16x16x32_bf16(af[kk], F1A[(nt*4+kk)*64 + lane], acc, 0,0,0);
            int col = nt*16 + l15;
            float bb = b1a_s[col], wc = w1c_s[col];
#pragma unroll
            for (int i = 0; i < 4; ++i){
                int r = quad*4 + i;
                x1s[r*264 + col] = (__bf16)fmaxf(acc[i] + bb + wc*sb_s[r], 0.f);
            }
        }
    }
    __syncthreads();

    // S2: x = x1 @ W1b^T + b1b, N=128 K=256 -> apre (reuse)
    {
        bf16x8 af[8];
#pragma unroll
        for (int kk = 0; kk < 8; ++kk)
            af[kk] = *(const bf16x8*)&x1s[l15*264 + kk*32 + quad*8];
#pragma unroll
        for (int j = 0; j < 2; ++j){
            int nt = wave*2 + j;
            f32x4 acc = {0.f,0.f,0.f,0.f};
#pragma unroll
            for (int kk = 0; kk < 8; ++kk)
                acc = __builtin_amdgcn_mfma_f32_16x16x32_bf16(af[kk], F1B[(nt*8+kk)*64 + lane], acc, 0,0,0);
            int col = nt*16 + l15;
#pragma unroll
            for (int i = 0; i < 4; ++i)
                apre[(quad*4+i)*136 + col] = (__bf16)(acc[i] + b1b_s[col]);
        }
    }
    __syncthreads();
    {   // vector store x
        int r = tid >> 4, seg = tid & 15;
        *(bf16x8*)&x_bf[(long)(b0 + r)*128 + seg*8] = *(const bf16x8*)&apre[r*136 + seg*8];
    }
}

// ---------------- actB: LSTM gates GEMM + elementwise ----------------------
// grid 512 = 64 M-tiles (64 rows) x 8 gate-col groups (32 cols/gate)
__global__ __launch_bounds__(256) void actB_kernel(
    const float* __restrict__ h0, const float* __restrict__ c0_in,
    const float* __restrict__ gb_ws, const __bf16* __restrict__ x_bf,
    const __bf16* __restrict__ wsbf,
    float* __restrict__ out_h, float* __restrict__ out_c, __bf16* __restrict__ h_bf)
{
    __shared__ __bf16 A[64*392];      // [x(128) | h0(256)] bf16, pad to 392
    __shared__ float gbs[128];

    int tid = threadIdx.x, blk = blockIdx.x;
    int m0 = (blk >> 3) * 64, c0 = blk & 7;

    // stage x part (bf16 copy)
    for (int ch = tid; ch < 1024; ch += 256){
        int r = ch >> 4, sg = ch & 15;
        *(bf16x8*)&A[r*392 + sg*8] = *(const bf16x8*)&x_bf[(long)(m0+r)*128 + sg*8];
    }
    // stage h0 part (fp32 -> bf16)
    for (int ch = tid; ch < 2048; ch += 256){
        int r = ch >> 5, sg = ch & 31;
        const float4* sp = (const float4*)(h0 + (long)(m0+r)*256 + sg*8);
        float4 a = sp[0], b = sp[1];
        *(bf16x8*)&A[r*392 + 128 + sg*8] = pack8(a, b);
    }
    if (tid < 128){ int g = tid >> 5, j = tid & 31; gbs[tid] = gb_ws[g*256 + c0*32 + j]; }
    __syncthreads();

    int wave = tid >> 6, lane = tid & 63, quad = lane >> 4, l15 = lane & 15;
    const bf16x8* FIH = (const bf16x8*)(wsbf + EL_WIH);
    const bf16x8* FHH = (const bf16x8*)(wsbf + EL_WHH);

    bf16x8 af[12];
#pragma unroll
    for (int kk = 0; kk < 12; ++kk)
        af[kk] = *(const bf16x8*)&A[(wave*16 + l15)*392 + kk*32 + quad*8];

#pragma unroll 1
    for (int t = 0; t < 2; ++t){
        int ct = c0*2 + t;                       // col-tile within a gate (0..15)
        f32x4 aI = {0.f,0.f,0.f,0.f}, aF = aI, aG = aI, aO = aI;
#pragma unroll
        for (int kk = 0; kk < 4; ++kk){
            aI = __builtin_amdgcn_mfma_f32_16x16x32_bf16(af[kk], FIH[(( 0+ct)*4+kk)*64 + lane], aI, 0,0,0);
            aF = __builtin_amdgcn_mfma_f32_16x16x32_bf16(af[kk], FIH[((16+ct)*4+kk)*64 + lane], aF, 0,0,0);
            aG = __builtin_amdgcn_mfma_f32_16x16x32_bf16(af[kk], FIH[((32+ct)*4+kk)*64 + lane], aG, 0,0,0);
            aO = __builtin_amdgcn_mfma_f32_16x16x32_bf16(af[kk], FIH[((48+ct)*4+kk)*64 + lane], aO, 0,0,0);
        }
#pragma unroll 4
        for (int k2 = 0; k2 < 8; ++k2){
            aI = __builtin_amdgcn_mfma_f32_16x16x32_bf16(af[4+k2], FHH[(( 0+ct)*8+k2)*64 + lane], aI, 0,0,0);
            aF = __builtin_amdgcn_mfma_f32_16x16x32_bf16(af[4+k2], FHH[((16+ct)*8+k2)*64 + lane], aF, 0,0,0);
            aG = __builtin_amdgcn_mfma_f32_16x16x32_bf16(af[4+k2], FHH[((32+ct)*8+k2)*64 + lane], aG, 0,0,0);
            aO = __builtin_amdgcn_mfma_f32_16x16x32_bf16(af[4+k2], FHH[((48+ct)*8+k2)*64 + lane], aO, 0,0,0);
        }
        int lc = t*16 + l15, hcol = c0*32 + lc;
        float bI = gbs[lc], bF = gbs[32+lc], bG = gbs[64+lc], bO = gbs[96+lc];
#pragma unroll
        for (int i = 0; i < 4; ++i){
            long row = m0 + wave*16 + quad*4 + i;
            float iv = aI[i]+bI, fv = aF[i]+bF, gv = aG[i]+bG, ov = aO[i]+bO;
            float cc = c0_in[row*256 + hcol];
            float cn = sigmoid_f(fv)*cc + sigmoid_f(iv)*tanh_f(gv);
            float hn = sigmoid_f(ov)*tanh_f(cn);
            out_c[row*256 + hcol] = cn;
            out_h[row*256 + hcol] = hn;
            h_bf[row*256 + hcol] = (__bf16)hn;
        }
    }
}

// ---------------- actC: emb = h@W3^T + b3; t = W2b^T emb; const ------------
__global__ __launch_bounds__(256) void actC_kernel(
    const __bf16* __restrict__ h_bf, const float* __restrict__ b3,
    const float* __restrict__ b2b, const __bf16* __restrict__ wsbf,
    __bf16* __restrict__ t_bf, float* __restrict__ const_ws)
{
    __shared__ __bf16 hs[16*264];
    __shared__ __bf16 es[16*136];
    __shared__ float b3_s[128], b2b_s[128];

    int tid = threadIdx.x, b0 = blockIdx.x * 16;
    if (tid < 128){ b3_s[tid] = b3[tid]; b2b_s[tid] = b2b[tid]; }
    for (int ch = tid; ch < 512; ch += 256){
        int r = ch >> 5, sg = ch & 31;
        *(bf16x8*)&hs[r*264 + sg*8] = *(const bf16x8*)&h_bf[(long)(b0+r)*256 + sg*8];
    }
    __syncthreads();

    int wave = tid >> 6, lane = tid & 63, quad = lane >> 4, l15 = lane & 15;
    const bf16x8* F3  = (const bf16x8*)(wsbf + EL_W3);
    const bf16x8* F2B = (const bf16x8*)(wsbf + EL_W2B);

    // S4: emb, N=128 K=256
    {
        bf16x8 af[8];
#pragma unroll
        for (int kk = 0; kk < 8; ++kk)
            af[kk] = *(const bf16x8*)&hs[l15*264 + kk*32 + quad*8];
#pragma unroll
        for (int j = 0; j < 2; ++j){
            int nt = wave*2 + j;
            f32x4 acc = {0.f,0.f,0.f,0.f};
#pragma unroll
            for (int kk = 0; kk < 8; ++kk)
                acc = __builtin_amdgcn_mfma_f32_16x16x32_bf16(af[kk], F3[(nt*8+kk)*64 + lane], acc, 0,0,0);
            int col = nt*16 + l15;
#pragma unroll
            for (int i = 0; i < 4; ++i)
                es[(quad*4+i)*136 + col] = (__bf16)(acc[i] + b3_s[col]);
        }
    }
    __syncthreads();

    // const[b] = dot(b2b, emb[b])
    {
        int r = tid >> 4, p = tid & 15;
        float s = 0.f;
#pragma unroll
        for (int q = 0; q < 8; ++q) s += b2b_s[p*8+q] * (float)es[r*136 + p*8 + q];
#pragma unroll
        for (int m = 1; m < 16; m <<= 1) s += __shfl_xor(s, m, 64);
        if (p == 0) const_ws[b0 + r] = s;
    }
    // S5: t = W2b^T emb, N=256 K=128 -> bf16 global
    {
        bf16x8 ef[4];
#pragma unroll
        for (int kk = 0; kk < 4; ++kk)
            ef[kk] = *(const bf16x8*)&es[l15*136 + kk*32 + quad*8];
#pragma unroll
        for (int j = 0; j < 4; ++j){
            int nt = wave*4 + j;
            f32x4 acc = {0.f,0.f,0.f,0.f};
#pragma unroll
            for (int kk = 0; kk < 4; ++kk)
                acc = __builtin_amdgcn_mfma_f32_16x16x32_bf16(ef[kk], F2B[(nt*4+kk)*64 + lane], acc, 0,0,0);
            int col = nt*16 + l15;
#pragma unroll
            for (int i = 0; i < 4; ++i)
                t_bf[(long)(b0 + quad*4 + i)*256 + col] = (__bf16)acc[i];
        }
    }
}

// ---------------- neighbor path: one batch row per block -------------------
template<bool GBF>
__global__ __launch_bounds__(256) void nei_kernel(
    const float* __restrict__ node_pre, const __bf16* __restrict__ node_bf,
    const float* __restrict__ steps, const float* __restrict__ b2a,
    const float* __restrict__ w2col, const int* __restrict__ neighbors,
    const int* __restrict__ deg, const __bf16* __restrict__ wsbf,
    const __bf16* __restrict__ t_bf, const float* __restrict__ const_ws,
    float* __restrict__ out_vals)
{
    __shared__ __bf16 at[64*136];
    __shared__ float t_s[256], bias_s[256], vp[256];

    int tid = threadIdx.x, b = blockIdx.x;
    float sb = steps[b] * 0.01f;
    t_s[tid]    = (float)t_bf[(long)b*256 + tid];
    bias_s[tid] = b2a[tid] + w2col[tid]*sb;
    {
        int r = tid >> 2, sg = tid & 3;
        long nb = neighbors[b*64 + r];
        if (GBF){
            const bf16x8* sp = (const bf16x8*)(node_bf + nb*128 + sg*32);
#pragma unroll
            for (int q = 0; q < 4; ++q) *(bf16x8*)&at[r*136 + sg*32 + q*8] = sp[q];
        } else {
            const float4* sp = (const float4*)(node_pre + nb*128 + sg*32);
#pragma unroll
            for (int q = 0; q < 4; ++q){
                float4 fa = sp[q*2], fb = sp[q*2+1];
                *(bf16x8*)&at[r*136 + sg*32 + q*8] = pack8(fa, fb);
            }
        }
    }
    __syncthreads();

    int wave = tid >> 6, lane = tid & 63, quad = lane >> 4, l15 = lane & 15;
    const bf16x8* FB = (const bf16x8*)(wsbf + EL_W2A);
    bf16x8 bw[16];
#pragma unroll
    for (int j = 0; j < 4; ++j){
        int nt = wave + 4*j;
#pragma unroll
        for (int kk = 0; kk < 4; ++kk) bw[j*4+kk] = FB[(nt*4+kk)*64 + lane];
    }

#pragma unroll 1
    for (int mt = 0; mt < 4; ++mt){
        bf16x8 af[4];
#pragma unroll
        for (int kk = 0; kk < 4; ++kk)
            af[kk] = *(const bf16x8*)&at[(mt*16 + l15)*136 + kk*32 + quad*8];
        f32x4 ps = {0.f,0.f,0.f,0.f};
#pragma unroll
        for (int j = 0; j < 4; ++j){
            int nt = wave + 4*j;
            f32x4 acc = {0.f,0.f,0.f,0.f};
#pragma unroll
            for (int kk = 0; kk < 4; ++kk)
                acc = __builtin_amdgcn_mfma_f32_16x16x32_bf16(af[kk], bw[j*4+kk], acc, 0,0,0);
            int col = nt*16 + l15;
            float bb = bias_s[col], tv = t_s[col];
#pragma unroll
            for (int i = 0; i < 4; ++i)
                ps[i] += fmaxf(acc[i] + bb, 0.f) * tv;
        }
#pragma unroll
        for (int m = 1; m < 16; m <<= 1){
#pragma unroll
            for (int i = 0; i < 4; ++i) ps[i] += __shfl_xor(ps[i], m, 64);
        }
        if (l15 == 0){
#pragma unroll
            for (int i = 0; i < 4; ++i) vp[wave*64 + mt*16 + quad*4 + i] = ps[i];
        }
    }
    __syncthreads();
    if (tid < 64){
        float v = vp[tid] + vp[64+tid] + vp[128+tid] + vp[192+tid];
        v = (v + const_ws[b]) * 0.08838834764831845f;   // 1/sqrt(128)
        int degb = deg[b]; if (degb < 1) degb = 1;
        if (tid >= degb) v = 0.f;
        out_vals[(long)b*64 + tid] = v;
    }
}

extern "C" void kernel_launch(void* const* d_in, const int* in_sizes, int n_in,
                              void* d_out, int out_size, void* d_ws, size_t ws_size,
                              hipStream_t stream)
{
    (void)in_sizes; (void)n_in; (void)out_size;
    const float* node_pre = (const float*)d_in[0];
    const float* steps    = (const float*)d_in[1];
    const float* h0       = (const float*)d_in[2];
    const float* c0       = (const float*)d_in[3];
    const float* W1a      = (const float*)d_in[4];
    const float* b1a      = (const float*)d_in[5];
    const float* W1b      = (const float*)d_in[6];
    const float* b1b      = (const float*)d_in[7];
    const float* W2a      = (const float*)d_in[8];
    const float* b2a      = (const float*)d_in[9];
    const float* W2b      = (const float*)d_in[10];
    const float* b2b      = (const float*)d_in[11];
    const float* W3       = (const float*)d_in[12];
    const float* b3       = (const float*)d_in[13];
    const float* Wih      = (const float*)d_in[14];
    const float* Whh      = (const float*)d_in[15];
    const float* bih      = (const float*)d_in[16];
    const float* bhh      = (const float*)d_in[17];
    const int* actions0   = (const int*)d_in[18];
    const int* neighbors  = (const int*)d_in[19];
    const int* deg        = (const int*)d_in[20];

    float* out      = (float*)d_out;
    float* out_vals = out;                       // [4096][64]
    float* out_h    = out + (long)BB*KK;         // [4096][256]
    float* out_c    = out_h + (long)BB*HH;       // [4096][256]

    __bf16* wsbf     = (__bf16*)d_ws;
    float* gb_ws     = (float*)((char*)d_ws + BOFF_GB);
    float* w1col_ws  = (float*)((char*)d_ws + BOFF_W1COL);
    float* w2col_ws  = (float*)((char*)d_ws + BOFF_W2COL);
    float* const_ws  = (float*)((char*)d_ws + BOFF_CONST);
    __bf16* x_bf     = (__bf16*)((char*)d_ws + BOFF_XT);
    __bf16* t_bf     = (__bf16*)((char*)d_ws + BOFF_XT);   // overlays x (x dead by actC)
    __bf16* h_bf     = (__bf16*)((char*)d_ws + BOFF_HBF);
    __bf16* node_bf  = (__bf16*)((char*)d_ws + BOFF_NODEBF);

    const bool full = (ws_size >= WS_NEED_FULL);

    if (full)
        conv_kernel<<<dim3(2048), dim3(256), 0, stream>>>(node_pre, node_bf);
    swz_kernel<<<dim3(1112), dim3(64), 0, stream>>>(W1a, W1b, Wih, Whh, W3, W2b, W2a,
                                                    bih, bhh, wsbf, gb_ws, w1col_ws, w2col_ws);
    actA_kernel<<<dim3(256), dim3(256), 0, stream>>>(node_pre, steps, actions0, b1a, b1b,
                                                     w1col_ws, wsbf, x_bf);
    actB_kernel<<<dim3(512), dim3(256), 0, stream>>>(h0, c0, gb_ws, x_bf, wsbf,
                                                     out_h, out_c, h_bf);
    actC_kernel<<<dim3(256), dim3(256), 0, stream>>>(h_bf, b3, b2b, wsbf, t_bf, const_ws);
    if (full)
        nei_kernel<true><<<dim3(4096), dim3(256), 0, stream>>>(node_pre, node_bf, steps, b2a,
                                                               w2col_ws, neighbors, deg, wsbf,
                                                               t_bf, const_ws, out_vals);
    else
        nei_kernel<false><<<dim3(4096), dim3(256), 0, stream>>>(node_pre, node_bf, steps, b2a,
                                                                w2col_ws, neighbors, deg, wsbf,
                                                                t_bf, const_ws, out_vals);
}